// Round 8
// baseline (3407.886 us; speedup 1.0000x reference)
//
#include <hip/hip_runtime.h>
#include <cstdint>

typedef __bf16 bf16;
typedef __bf16 bf16x8 __attribute__((ext_vector_type(8)));

#define DEV __device__ __forceinline__

static const int LL = 4096, HH = 1024, NCH = 128;

DEV float b2f(bf16 x){ return (float)x; }
DEV bf16  f2b(float x){ return (bf16)x; }

// ---------------- GEMM: C[M,N] = A[M,K] * B[K,N], B f32 natural [K,N] ----------------
// AF32: A f32 (converted on the fly) else bf16. EPI=1: +bias, exact gelu. OF32: C f32 else bf16.
template<int EPI, int AF32, int OF32>
__global__ __launch_bounds__(256) void k_gemm_f(const void* __restrict__ Ap, const float* __restrict__ B,
    const float* __restrict__ bias, void* __restrict__ Cp, int M, int N, int K){
  __shared__ __align__(16) bf16 As[64*32];
  __shared__ __align__(16) float Bs[32*64];
  int t = threadIdx.x;
  int tx = t & 15, ty = t >> 4;
  int m0 = blockIdx.y*64, n0 = blockIdx.x*64;
  float acc[4][4];
  #pragma unroll
  for(int i=0;i<4;i++)
    #pragma unroll
    for(int j=0;j<4;j++) acc[i][j]=0.f;
  int srow = t>>2, ssub = (t&3)*8;      // A stage: 64 rows x 32 k
  int brow = t>>3, bcol = (t&7)*8;      // B stage: 32 k-rows x 64 n-cols
  for(int k0=0;k0<K;k0+=32){
    if(AF32){
      const float* Af = (const float*)Ap;
      float4 p0 = *(const float4*)(Af + (size_t)(m0+srow)*K + k0 + ssub);
      float4 p1 = *(const float4*)(Af + (size_t)(m0+srow)*K + k0 + ssub + 4);
      bf16* dst = &As[srow*32+ssub];
      dst[0]=f2b(p0.x); dst[1]=f2b(p0.y); dst[2]=f2b(p0.z); dst[3]=f2b(p0.w);
      dst[4]=f2b(p1.x); dst[5]=f2b(p1.y); dst[6]=f2b(p1.z); dst[7]=f2b(p1.w);
    } else {
      *(bf16x8*)&As[srow*32+ssub] = *(const bf16x8*)((const bf16*)Ap + (size_t)(m0+srow)*K + k0 + ssub);
    }
    *(float4*)&Bs[brow*64+bcol]   = *(const float4*)(B + (size_t)(k0+brow)*N + n0 + bcol);
    *(float4*)&Bs[brow*64+bcol+4] = *(const float4*)(B + (size_t)(k0+brow)*N + n0 + bcol + 4);
    __syncthreads();
    for(int kk=0;kk<32;kk++){
      float av[4], bv[4];
      #pragma unroll
      for(int i=0;i<4;i++) av[i] = b2f(As[(ty*4+i)*32+kk]);
      #pragma unroll
      for(int j=0;j<4;j++) bv[j] = Bs[kk*64 + tx*4+j];
      #pragma unroll
      for(int i=0;i<4;i++)
        #pragma unroll
        for(int j=0;j<4;j++) acc[i][j] += av[i]*bv[j];
    }
    __syncthreads();
  }
  #pragma unroll
  for(int i=0;i<4;i++)
    #pragma unroll
    for(int j=0;j<4;j++){
      int gm = m0+ty*4+i, gn = n0+tx*4+j;
      float v = acc[i][j];
      if(EPI==1){ v += bias[gn]; v = 0.5f*v*(1.f + erff(v*0.70710678118f)); }
      if(OF32) ((float*)Cp)[(size_t)gm*N + gn] = v;
      else     ((bf16*)Cp)[(size_t)gm*N + gn] = f2b(v);
    }
}

// ---------------- beta = sigmoid(hs @ Wb), hs f32 ----------------
__global__ __launch_bounds__(256) void k_beta(const float* __restrict__ X, const float* __restrict__ Wb,
                                              float* __restrict__ beta){
  int row = blockIdx.x*4 + (threadIdx.x>>6), lane = threadIdx.x&63;
  const float* xp = X + (size_t)row*HH;
  float a0=0,a1=0,a2=0,a3=0;
  for(int k=lane;k<HH;k+=64){
    float x = xp[k];
    float4 wr = *(const float4*)(Wb + (size_t)k*4);
    a0 += x*wr.x; a1 += x*wr.y; a2 += x*wr.z; a3 += x*wr.w;
  }
  #pragma unroll
  for(int off=32;off>=1;off>>=1){
    a0 += __shfl_down(a0,off,64); a1 += __shfl_down(a1,off,64);
    a2 += __shfl_down(a2,off,64); a3 += __shfl_down(a3,off,64);
  }
  if(lane==0){
    beta[(size_t)row*4+0] = 1.f/(1.f+__expf(-a0));
    beta[(size_t)row*4+1] = 1.f/(1.f+__expf(-a1));
    beta[(size_t)row*4+2] = 1.f/(1.f+__expf(-a2));
    beta[(size_t)row*4+3] = 1.f/(1.f+__expf(-a3));
  }
}

// ---------------- depthwise causal conv K=4 + silu (+ per-head l2norm) ----------------
__global__ __launch_bounds__(256) void k_conv4(const bf16* __restrict__ pre, const float* __restrict__ filt,
                                               bf16* __restrict__ outp, int do_norm){
  __shared__ float red[4][8];
  int tx = threadIdx.x, head = blockIdx.y, b = blockIdx.z; int l0 = blockIdx.x*64;
  int wv = tx>>6, lane = tx&63;
  int c = head*256 + tx;
  const bf16* p = pre + (size_t)b*LL*HH + c;
  const float* fp = filt + (size_t)c*4;
  float f0=fp[0], f1=fp[1], f2=fp[2], f3=fp[3];
  float x0,x1,x2;
  if(l0>0){ x0=b2f(p[(size_t)(l0-3)*HH]); x1=b2f(p[(size_t)(l0-2)*HH]); x2=b2f(p[(size_t)(l0-1)*HH]); }
  else { x0=x1=x2=0.f; }
  for(int g=0; g<8; g++){
    float y[8];
    #pragma unroll
    for(int i=0;i<8;i++){
      int l = l0+g*8+i;
      float x3 = b2f(p[(size_t)l*HH]);
      float u = f0*x0 + f1*x1 + f2*x2 + f3*x3;
      x0=x1; x1=x2; x2=x3;
      y[i] = u/(1.f+__expf(-u));
    }
    if(do_norm){
      float sq[8];
      #pragma unroll
      for(int i=0;i<8;i++) sq[i]=y[i]*y[i];
      #pragma unroll
      for(int off=32;off>=1;off>>=1)
        #pragma unroll
        for(int i=0;i<8;i++) sq[i] += __shfl_down(sq[i],off,64);
      if(lane==0){
        #pragma unroll
        for(int i=0;i<8;i++) red[wv][i]=sq[i];
      }
      __syncthreads();
      float tot[8];
      #pragma unroll
      for(int i=0;i<8;i++) tot[i]=red[0][i]+red[1][i]+red[2][i]+red[3][i];
      __syncthreads();
      #pragma unroll
      for(int i=0;i<8;i++) y[i] *= rsqrtf(tot[i]);
    }
    #pragma unroll
    for(int i=0;i<8;i++) outp[(size_t)(b*LL + l0+g*8+i)*HH + c] = f2b(y[i]);
  }
}

// ---------------- gate: softmax4(h1 @ Wf2 + bf2), Wf2 f32 [2048][16] ----------------
__global__ __launch_bounds__(256) void k_gate(const bf16* __restrict__ h1, const float* __restrict__ W2,
                                              const float* __restrict__ bf2v, float* __restrict__ fw){
  int row = blockIdx.x*4 + (threadIdx.x>>6), lane = threadIdx.x&63;
  const bf16* hp = h1 + (size_t)row*2048;
  float acc[16];
  #pragma unroll
  for(int c=0;c<16;c++) acc[c]=0.f;
  for(int k=lane;k<2048;k+=64){
    float x = b2f(hp[k]);
    const float* wr = W2 + (size_t)k*16;
    float4 w0 = *(const float4*)(wr), w1 = *(const float4*)(wr+4);
    float4 w2 = *(const float4*)(wr+8), w3 = *(const float4*)(wr+12);
    acc[0]+=x*w0.x; acc[1]+=x*w0.y; acc[2]+=x*w0.z; acc[3]+=x*w0.w;
    acc[4]+=x*w1.x; acc[5]+=x*w1.y; acc[6]+=x*w1.z; acc[7]+=x*w1.w;
    acc[8]+=x*w2.x; acc[9]+=x*w2.y; acc[10]+=x*w2.z; acc[11]+=x*w2.w;
    acc[12]+=x*w3.x; acc[13]+=x*w3.y; acc[14]+=x*w3.z; acc[15]+=x*w3.w;
  }
  #pragma unroll
  for(int off=32;off>=1;off>>=1)
    #pragma unroll
    for(int c=0;c<16;c++) acc[c] += __shfl_down(acc[c],off,64);
  if(lane==0){
    #pragma unroll
    for(int h=0;h<4;h++){
      float s0=acc[h*4+0]+bf2v[h*4+0], s1=acc[h*4+1]+bf2v[h*4+1];
      float s2=acc[h*4+2]+bf2v[h*4+2], s3=acc[h*4+3]+bf2v[h*4+3];
      float mx = fmaxf(fmaxf(s0,s1),fmaxf(s2,s3));
      float e0=__expf(s0-mx), e1=__expf(s1-mx), e2=__expf(s2-mx), e3=__expf(s3-mx);
      float inv = 1.f/(e0+e1+e2+e3);
      fw[(size_t)row*16+h*4+0]=e0*inv; fw[(size_t)row*16+h*4+1]=e1*inv;
      fw[(size_t)row*16+h*4+2]=e2*inv; fw[(size_t)row*16+h*4+3]=e3*inv;
    }
  }
}

// ---------------- per-chunk precompute (VALU): T, u, w, attn ----------------
__global__ __launch_bounds__(256) void k_pre2(const bf16* __restrict__ qn, const bf16* __restrict__ kn,
    const bf16* __restrict__ vv, const float* __restrict__ beta,
    bf16* __restrict__ uFb, bf16* __restrict__ wFb, float* __restrict__ aF){
  __shared__ __align__(16) bf16 qs[8192], ks[8192], vs[8192];
  __shared__ float T[32][33];
  __shared__ float bet[32];
  int ch = blockIdx.x, bh = blockIdx.y, b = bh>>2, h = bh&3;
  int t = threadIdx.x;
  int l0 = ch*32;
  size_t rowbase = ((size_t)(b*LL+l0))*HH + h*256;
  #pragma unroll
  for(int i=0;i<4;i++){
    int f = i*256+t, row = f>>5, sub = f&31;
    size_t go = rowbase + (size_t)row*HH + sub*8;
    *(bf16x8*)&qs[f*8] = *(const bf16x8*)(qn+go);
    *(bf16x8*)&ks[f*8] = *(const bf16x8*)(kn+go);
    *(bf16x8*)&vs[f*8] = *(const bf16x8*)(vv+go);
  }
  if(t<32) bet[t] = beta[(size_t)(b*LL+l0+t)*4 + h];
  __syncthreads();
  int c = t>>3, e0 = (t&7)*4;
  float d0=0,d1=0,d2=0,d3=0, a0=0,a1=0,a2=0,a3=0;
  for(int d=0; d<256; d++){
    float kc = b2f(ks[c*256+d]);
    float qc = b2f(qs[c*256+d]);
    float k0 = b2f(ks[(e0+0)*256+d]);
    float k1 = b2f(ks[(e0+1)*256+d]);
    float k2 = b2f(ks[(e0+2)*256+d]);
    float k3 = b2f(ks[(e0+3)*256+d]);
    d0 += kc*k0; d1 += kc*k1; d2 += kc*k2; d3 += kc*k3;
    a0 += qc*k0; a1 += qc*k1; a2 += qc*k2; a3 += qc*k3;
  }
  float bc = bet[c];
  T[c][e0+0] = (c>e0+0)? -bc*d0 : 0.f;
  T[c][e0+1] = (c>e0+1)? -bc*d1 : 0.f;
  T[c][e0+2] = (c>e0+2)? -bc*d2 : 0.f;
  T[c][e0+3] = (c>e0+3)? -bc*d3 : 0.f;
  size_t ab = ((size_t)(bh*NCH+ch))*1024;
  aF[ab + c*32 + e0+0] = (c>=e0+0)? a0 : 0.f;
  aF[ab + c*32 + e0+1] = (c>=e0+1)? a1 : 0.f;
  aF[ab + c*32 + e0+2] = (c>=e0+2)? a2 : 0.f;
  aF[ab + c*32 + e0+3] = (c>=e0+3)? a3 : 0.f;
  __syncthreads();
  // forward substitution — lanes 0..31 of wave 0, lockstep; volatile forces LDS traffic
  if(t < 32){
    volatile float (*Tv)[33] = (volatile float (*)[33])T;
    int j = t;
    for(int i=1;i<32;i++){
      float s2 = 0.f;
      for(int m=0;m<i;m++) s2 += Tv[i][m]*Tv[m][j];
      Tv[i][j] += s2;
    }
    Tv[j][j] += 1.f;
  }
  __syncthreads();
  int dv0 = (t&7)*32;
  float uacc[32], wacc[32];
  #pragma unroll
  for(int j=0;j<32;j++){ uacc[j]=0.f; wacc[j]=0.f; }
  for(int c2=0;c2<32;c2++){
    float coef = T[c][c2]*bet[c2];
    #pragma unroll
    for(int j=0;j<32;j++){
      uacc[j] += coef * b2f(vs[c2*256+dv0+j]);
      wacc[j] += coef * b2f(ks[c2*256+dv0+j]);
    }
  }
  size_t ub = ((size_t)(bh*NCH+ch))*8192 + (size_t)c*256 + dv0;
  #pragma unroll
  for(int j=0;j<32;j++){ uFb[ub+j] = f2b(uacc[j]); wFb[ub+j] = f2b(wacc[j]); }
}

// ---------------- sequential chunkwise scan (VALU, S in LDS) ----------------
__global__ __launch_bounds__(256,1) void k_scan2(const bf16* __restrict__ qn, const bf16* __restrict__ kn,
    const bf16* __restrict__ uFb, const bf16* __restrict__ wFb, const float* __restrict__ aF,
    bf16* __restrict__ delta){
  __shared__ float S[256][17];
  __shared__ float ut[32][17];
  int dvs = blockIdx.x, bh = blockIdx.y, b = bh>>2, h = bh&3;
  int t = threadIdx.x;
  int c = t>>3, jj = t&7, j0 = jj*2;
  for(int j=0;j<16;j++) S[t][j] = 0.f;
  __syncthreads();
  for(int ci=0; ci<NCH; ci++){
    size_t cb = (size_t)(bh*NCH+ci);
    size_t tokbase = ((size_t)(b*LL + ci*32 + c))*HH + h*256;
    const bf16* wrow = wFb + cb*8192 + (size_t)c*256;
    const bf16* qrow = qn + tokbase;
    float u0 = b2f(uFb[cb*8192 + (size_t)c*256 + dvs*16 + j0]);
    float u1 = b2f(uFb[cb*8192 + (size_t)c*256 + dvs*16 + j0+1]);
    float o0 = 0.f, o1 = 0.f;
    for(int dk=0; dk<256; dk++){
      float wv = b2f(wrow[dk]), qv = b2f(qrow[dk]);
      float s0 = S[dk][j0], s1 = S[dk][j0+1];
      u0 -= wv*s0; u1 -= wv*s1;
      o0 += qv*s0; o1 += qv*s1;
    }
    ut[c][j0] = u0; ut[c][j0+1] = u1;
    __syncthreads();
    const float* arow = aF + cb*1024 + (size_t)c*32;
    for(int c2=0; c2<=c; c2++){
      float av = arow[c2];
      o0 += av*ut[c2][j0]; o1 += av*ut[c2][j0+1];
    }
    delta[tokbase + dvs*16 + j0]   = f2b(o0);
    delta[tokbase + dvs*16 + j0+1] = f2b(o1);
    {
      const bf16* kcol = kn + ((size_t)(b*LL + ci*32))*HH + h*256 + t;
      float acc[16];
      #pragma unroll
      for(int j=0;j<16;j++) acc[j] = 0.f;
      for(int c2=0;c2<32;c2++){
        float kv = b2f(kcol[(size_t)c2*HH]);
        #pragma unroll
        for(int j=0;j<16;j++) acc[j] += kv*ut[c2][j];
      }
      #pragma unroll
      for(int j=0;j<16;j++) S[t][j] += acc[j];
    }
    __syncthreads();
  }
}

// ---------------- FIR convs + gated fusion + RMSNorm ----------------
__global__ __launch_bounds__(256) void k_fuse(const bf16* __restrict__ vv, const bf16* __restrict__ delta,
    const float* __restrict__ fw, const float* __restrict__ fsw, const float* __restrict__ flw,
    const float* __restrict__ rmsw, bf16* __restrict__ fused){
  __shared__ float red[4][8];
  int tx = threadIdx.x, head = blockIdx.y, b = blockIdx.z; int l0 = blockIdx.x*64;
  int wv = tx>>6, lane = tx&63;
  int c = head*256 + tx;
  const bf16* vp = vv + (size_t)b*LL*HH + c;
  float fs[7], fl[64];
  #pragma unroll
  for(int j=0;j<7;j++) fs[j] = fsw[(size_t)c*7+j];
  #pragma unroll
  for(int j=0;j<64;j++) fl[j] = flw[(size_t)c*64+j];
  float win[64];
  #pragma unroll
  for(int i=0;i<63;i++){ int l=l0-63+i; win[i] = (l>=0)? b2f(vp[(size_t)l*HH]) : 0.f; }
  float rw = rmsw[tx];
  for(int g=0; g<8; g++){
    float oo[8], sq[8];
    #pragma unroll
    for(int i=0;i<8;i++){
      int s = g*8+i; int l = l0+s;
      win[(s+63)&63] = b2f(vp[(size_t)l*HH]);
      float ll2 = 0.f;
      #pragma unroll
      for(int tp=0;tp<64;tp++) ll2 += fl[tp]*win[(s+tp)&63];
      float ls = 0.f;
      #pragma unroll
      for(int tp=0;tp<7;tp++) ls += fs[tp]*win[(s+57+tp)&63];
      float dl = b2f(delta[(size_t)(b*LL+l)*HH + c]);
      float vh = win[(s+63)&63];
      const float* fp = fw + (size_t)(b*LL+l)*16 + head*4;
      float o = fp[0]*ls + fp[1]*ll2 + fp[2]*dl + fp[3]*vh;
      oo[i]=o; sq[i]=o*o;
    }
    #pragma unroll
    for(int off=32;off>=1;off>>=1)
      #pragma unroll
      for(int i=0;i<8;i++) sq[i] += __shfl_down(sq[i],off,64);
    if(lane==0){
      #pragma unroll
      for(int i=0;i<8;i++) red[wv][i]=sq[i];
    }
    __syncthreads();
    float tot[8];
    #pragma unroll
    for(int i=0;i<8;i++) tot[i]=red[0][i]+red[1][i]+red[2][i]+red[3][i];
    __syncthreads();
    #pragma unroll
    for(int i=0;i<8;i++){
      int l = l0+g*8+i;
      fused[(size_t)(b*LL+l)*HH + c] = f2b(oo[i]*rsqrtf(tot[i]*(1.f/256.f)+1e-5f)*rw);
    }
  }
}

extern "C" void kernel_launch(void* const* d_in, const int* in_sizes, int n_in,
                              void* d_out, int out_size, void* d_ws, size_t ws_size,
                              hipStream_t stream){
  // Inputs f32 (reference dtype), OUTPUT f32 (reference output dtype) — R7 post-mortem.
  const float* hs  =(const float*)d_in[0];
  const float* Wq  =(const float*)d_in[1];
  const float* Wk  =(const float*)d_in[2];
  const float* Wv  =(const float*)d_in[3];
  const float* Wb  =(const float*)d_in[4];
  const float* cqw =(const float*)d_in[5];
  const float* ckw =(const float*)d_in[6];
  const float* cvw =(const float*)d_in[7];
  const float* fsw =(const float*)d_in[8];
  const float* flw =(const float*)d_in[9];
  const float* Wf1 =(const float*)d_in[10];
  const float* bf1 =(const float*)d_in[11];
  const float* Wf2 =(const float*)d_in[12];
  const float* bf2v=(const float*)d_in[13];
  const float* rmsw=(const float*)d_in[14];
  const float* Wo  =(const float*)d_in[15];

  char* ws = (char*)d_ws;
  size_t off = 0;
  auto alloc = [&](size_t bytes)->char*{
    char* p = ws + off; off = (off + bytes + 255) & ~(size_t)255; return p;
  };
  bf16* pre   = (bf16*)alloc(8192ull*1024*2);   // q/k/v pre-conv (sequential); later fusedb
  bf16* qn    = (bf16*)alloc(8192ull*1024*2);
  bf16* kn    = (bf16*)alloc(8192ull*1024*2);
  bf16* vvb   = (bf16*)alloc(8192ull*1024*2);
  float* beta = (float*)alloc(8192ull*4*4);
  bf16* uFb   = (bf16*)alloc(8ull*128*8192*2);  // h1 aliases uFb+wFb (32MB) before k_pre2
  bf16* wFb   = (bf16*)alloc(8ull*128*8192*2);
  float* aF   = (float*)alloc(8ull*128*1024*4);
  float* fw   = (float*)alloc(8192ull*16*4);
  bf16* h1    = uFb;                            // dead once fw extracted
  bf16* dlt   = (bf16*)d_out;                   // first 16MB of the 32MB f32 out; dead before final GEMM
  bf16* fusedb= pre;                            // pre dead after conv v
  float* outb = (float*)d_out;

  dim3 b256(256);
  // q path
  k_gemm_f<0,1,0><<<dim3(16,128), b256, 0, stream>>>(hs, Wq, nullptr, pre, 8192, 1024, 1024);
  k_conv4<<<dim3(64,4,2), b256, 0, stream>>>(pre, cqw, qn, 1);
  // k path
  k_gemm_f<0,1,0><<<dim3(16,128), b256, 0, stream>>>(hs, Wk, nullptr, pre, 8192, 1024, 1024);
  k_conv4<<<dim3(64,4,2), b256, 0, stream>>>(pre, ckw, kn, 1);
  // v path
  k_gemm_f<0,1,0><<<dim3(16,128), b256, 0, stream>>>(hs, Wv, nullptr, pre, 8192, 1024, 1024);
  k_conv4<<<dim3(64,4,2), b256, 0, stream>>>(pre, cvw, vvb, 0);
  // beta
  k_beta<<<dim3(2048), b256, 0, stream>>>(hs, Wb, beta);
  // gate (before k_pre2: h1 aliases uFb/wFb)
  k_gemm_f<1,1,0><<<dim3(32,128), b256, 0, stream>>>(hs, Wf1, bf1, h1, 8192, 2048, 1024);
  k_gate<<<dim3(2048), b256, 0, stream>>>(h1, Wf2, bf2v, fw);
  // delta rule
  k_pre2<<<dim3(128,8), b256, 0, stream>>>(qn, kn, vvb, beta, uFb, wFb, aF);
  k_scan2<<<dim3(16,8), b256, 0, stream>>>(qn, kn, uFb, wFb, aF, dlt);
  // fuse + output projection (f32 out)
  k_fuse<<<dim3(64,4,2), b256, 0, stream>>>(vvb, dlt, fw, fsw, flw, rmsw, fusedb);
  k_gemm_f<0,0,1><<<dim3(16,128), b256, 0, stream>>>(fusedb, Wo, nullptr, outb, 8192, 1024, 1024);

  (void)in_sizes; (void)n_in; (void)out_size; (void)ws_size;
}